// Round 1
// 178.674 us; speedup vs baseline: 1.0118x; 1.0118x over previous
//
#include <hip/hip_runtime.h>

// RegLoss: l1(masked preds, targets) + 0.1 * mse(masked edge directions)
// preds, targets: [128, 1024, 151] fp32. Output: 1 fp32 scalar.
//
// Identities:
//   targets * (targets != 0) == targets       (masking targets is identity)
//   (m*pd - m*td)^2 == m*(pd - td)^2          (m in {0,1})
//   diff/(len+tiny) == (d2 > 0 ? diff*rsq(d2) : 0)  (~1e-7 rel; thresh 2.4e-2)
//
// R7: occupancy over pipeline depth. R6's depth-2 LDS double buffer cost
// 9664 B/wave -> 38.9 KB/block -> only 4 blocks/CU (50% wave cap, 31%
// measured) and 2 dispatch rounds; with ~10 resident waves/CU the loaded
// memory latency couldn't be hidden (2.5 TB/s effective, VALUBusy 19%).
// In-flight LDS bytes = chunk_size x depth, so depth and occupancy compete:
// we keep the 4-row chunk (the smallest granule whose global addresses stay
// 16B-aligned for global_load_lds; 151 dwords/row is odd) and drop to a
// SINGLE buffer: 4832 B/wave -> 19.3 KB/block -> 8 blocks/CU, 32 waves/CU
// (100% cap), entire 2048-block grid co-resident in one round. Per-wave the
// chunk loop is serial (DMA -> vmcnt(0) -> compute), but 8 waves/SIMD of TLP
// hide the latency; avg outstanding DMA per CU ~116 KB keeps HBM fed.
// __launch_bounds__(256,8) pins VGPRs <= 64 (was 52) so occupancy holds.

#define N_ROWS   (128 * 1024)
#define ROW      151
#define N_EDGES  47
#define GRID     2048
#define BLOCK    256
#define CHUNKS   4                     // 2048 blk * 4 waves * 4 chunks * 4 rows
#define CHUNK_ROWS 4
#define CHUNK_DW (CHUNK_ROWS * ROW)    // 604 dwords per array per chunk
#define CHUNK_TASKS (CHUNK_ROWS * N_EDGES) // 188
#define BUF_DW (2 * CHUNK_DW)          // [preds 604][targets 604] = 4832 B

#if __has_builtin(__builtin_amdgcn_rsqf)
__device__ __forceinline__ float fast_rsq(float x) { return __builtin_amdgcn_rsqf(x); }
#else
__device__ __forceinline__ float fast_rsq(float x) {
    float r; asm volatile("v_rsq_f32 %0, %1" : "=v"(r) : "v"(x)); return r;
}
#endif

template <int N>
__device__ __forceinline__ void wait_vm() {
    asm volatile("s_waitcnt vmcnt(%0)" :: "n"(N) : "memory");
}
__device__ __forceinline__ void wait_lgkm0() {
    asm volatile("s_waitcnt lgkmcnt(0)" ::: "memory");
}

__device__ __forceinline__ void dma16(const float* g, float* l) {
    __builtin_amdgcn_global_load_lds(
        (const __attribute__((address_space(1))) unsigned*)g,
        (__attribute__((address_space(3))) unsigned*)l, 16, 0, 0);
}

// 6 DMA instructions per chunk: 2x1024B + 368B tail per array.
__device__ __forceinline__ void dma_chunk(const float* gp, const float* gt,
                                          float* L, int lane) {
    const int l4 = lane * 4;
    dma16(gp + l4,        L);
    dma16(gp + 256 + l4,  L + 256);
    dma16(gt + l4,        L + CHUNK_DW);
    dma16(gt + 256 + l4,  L + CHUNK_DW + 256);
    if (lane < 23) {                       // 23*16B = 368B tail (604-512 dw)
        dma16(gp + 512 + l4, L + 512);
        dma16(gt + 512 + l4, L + CHUNK_DW + 512);
    }
}

// packed: low16 = parent*3 (dword offset in row), high16 = child*3
#define E(p, c) ((unsigned)((p) * 3) | ((unsigned)((c) * 3) << 16))
__constant__ unsigned c_edge[N_EDGES] = {
    E(0,1),  E(1,2),  E(2,3),  E(3,29), E(1,5),  E(5,6),  E(6,8),  E(8,9),
    E(8,13), E(8,17), E(8,21), E(8,25), E(9,10), E(10,11),E(11,12),E(13,14),
    E(14,15),E(15,16),E(17,18),E(18,19),E(19,20),E(21,22),E(22,23),E(23,24),
    E(25,26),E(26,27),E(27,28),E(29,30),E(29,34),E(29,38),E(29,42),E(29,46),
    E(30,31),E(31,32),E(32,33),E(34,35),E(35,36),E(36,37),E(38,39),E(39,40),
    E(40,41),E(42,43),E(43,44),E(44,45),E(46,47),E(47,48),E(48,49)};

struct TaskDesc { int act[3], roff[3], pi[3], ci[3], me[3]; };

__device__ __forceinline__ void compute_chunk(
        const float* __restrict__ B, int lane, const TaskDesc& td,
        float& l1, float& vel) {
    const float* __restrict__ Bp = B;
    const float* __restrict__ Bt = B + CHUNK_DW;

    // ---- l1 over the chunk: lane-contiguous b128 LDS reads ----
#pragma unroll
    for (int k = 0; k < 3; ++k) {
        int i = lane + k * 64;
        if (i < CHUNK_DW / 4) {
            float4 pv = ((const float4*)Bp)[i];
            float4 tv = ((const float4*)Bt)[i];
            float a0 = (tv.x != 0.f) ? pv.x : 0.f;
            float a1 = (tv.y != 0.f) ? pv.y : 0.f;
            float a2 = (tv.z != 0.f) ? pv.z : 0.f;
            float a3 = (tv.w != 0.f) ? pv.w : 0.f;
            l1 += fabsf(a0 - tv.x) + fabsf(a1 - tv.y)
                + fabsf(a2 - tv.z) + fabsf(a3 - tv.w);
        }
    }

    // ---- 188 edge tasks, mask applied at read time ----
#pragma unroll
    for (int k = 0; k < 3; ++k) {
        if (td.act[k]) {
            const float* __restrict__ Rp = Bp + td.roff[k];
            const float* __restrict__ Rt = Bt + td.roff[k];
            int pi = td.pi[k], ci = td.ci[k], me = td.me[k];
            float tpx = Rt[pi], tpy = Rt[pi + 1], tpz = Rt[pi + 2];
            float tcx = Rt[ci], tcy = Rt[ci + 1], tcz = Rt[ci + 2];
            float ppx = Rp[pi], ppy = Rp[pi + 1], ppz = Rp[pi + 2];
            float pcx = Rp[ci], pcy = Rp[ci + 1], pcz = Rp[ci + 2];
            // masked preds
            float apx = (tpx != 0.f) ? ppx : 0.f;
            float apy = (tpy != 0.f) ? ppy : 0.f;
            float apz = (tpz != 0.f) ? ppz : 0.f;
            float acx = (tcx != 0.f) ? pcx : 0.f;
            float acy = (tcy != 0.f) ? pcy : 0.f;
            float acz = (tcz != 0.f) ? pcz : 0.f;
            float pdx = apx - acx, pdy = apy - acy, pdz = apz - acz;
            float tdx = tpx - tcx, tdy = tpy - tcy, tdz = tpz - tcz;
            float pd2 = pdx * pdx + pdy * pdy + pdz * pdz;
            float td2 = tdx * tdx + tdy * tdy + tdz * tdz;
            float pinv = (pd2 > 0.f) ? fast_rsq(pd2) : 0.f;
            float tinv = (td2 > 0.f) ? fast_rsq(td2) : 0.f;
            float dx = pdx * pinv - tdx * tinv;
            float dy = pdy * pinv - tdy * tinv;
            float dz = pdz * pinv - tdz * tinv;
            float m0 = (Rt[me]      != 0.f) ? 1.f : 0.f;
            float m1 = (Rt[me + 47] != 0.f) ? 1.f : 0.f;
            float m2 = (Rt[me + 94] != 0.f) ? 1.f : 0.f;
            vel += m0 * dx * dx + m1 * dy * dy + m2 * dz * dz;
        }
    }
}

__global__ __launch_bounds__(BLOCK, 8) void reg_loss_main(
        const float* __restrict__ preds, const float* __restrict__ targets,
        float* __restrict__ wsL, float* __restrict__ wsV) {
    __shared__ float S[4][BUF_DW];         // 4 waves x 4832B = 19.3 KB/block
    __shared__ float redL[4], redV[4];

    const int t = threadIdx.x;
    const int lane = t & 63;
    const int wave = t >> 6;
    float* B = &S[wave][0];

    const long long wb =
        (long long)(blockIdx.x * 4 + wave) * (CHUNKS * CHUNK_DW);
    const float* gp = preds + wb;
    const float* gt = targets + wb;

    // per-lane edge-task descriptors (fixed across chunks)
    TaskDesc td;
#pragma unroll
    for (int k = 0; k < 3; ++k) {
        int task = lane + k * 64;
        td.act[k] = task < CHUNK_TASKS;
        int r = task / N_EDGES;
        int e = task - r * N_EDGES;
        if (!td.act[k]) { r = 0; e = 0; }
        td.roff[k] = r * ROW;
        unsigned pk = c_edge[e];
        td.pi[k] = pk & 0xffff;
        td.ci[k] = pk >> 16;
        td.me[k] = e;
    }

    // ---- depth-1 chunk loop; latency hidden by 32 waves/CU of TLP ----
    dma_chunk(gp, gt, B, lane);            // chunk 0

    float l1 = 0.f, vel = 0.f;

#pragma unroll
    for (int c = 0; c < CHUNKS; ++c) {
        wait_vm<0>();                      // chunk c landed in LDS
        compute_chunk(B, lane, td, l1, vel);
        if (c + 1 < CHUNKS) {
            wait_lgkm0();                  // LDS reads retired before overwrite
            dma_chunk(gp + (c + 1) * CHUNK_DW, gt + (c + 1) * CHUNK_DW,
                      B, lane);
        }
    }

    // ---- block reduction -> per-block partials ----
#pragma unroll
    for (int off = 32; off > 0; off >>= 1) {
        l1  += __shfl_down(l1, off);
        vel += __shfl_down(vel, off);
    }
    if (lane == 0) { redL[wave] = l1; redV[wave] = vel; }
    __syncthreads();
    if (t == 0) {
        wsL[blockIdx.x] = redL[0] + redL[1] + redL[2] + redL[3];
        wsV[blockIdx.x] = redV[0] + redV[1] + redV[2] + redV[3];
    }
}

__global__ __launch_bounds__(BLOCK) void reg_loss_finalize(
        const float* __restrict__ wsL, const float* __restrict__ wsV,
        float* __restrict__ out) {
    __shared__ double rl[4], rv[4];
    const int t = threadIdx.x;
    const int lane = t & 63;
    const int wave = t >> 6;
    double L = 0.0, V = 0.0;
    for (int k = t; k < GRID; k += BLOCK) { L += wsL[k]; V += wsV[k]; }
#pragma unroll
    for (int off = 32; off > 0; off >>= 1) {
        L += __shfl_down(L, off);
        V += __shfl_down(V, off);
    }
    if (lane == 0) { rl[wave] = L; rv[wave] = V; }
    __syncthreads();
    if (t == 0) {
        double Ls = rl[0] + rl[1] + rl[2] + rl[3];
        double Vs = rv[0] + rv[1] + rv[2] + rv[3];
        out[0] = (float)(Ls / ((double)N_ROWS * 151.0)
                       + 0.1 * (Vs / ((double)N_ROWS * 141.0)));
    }
}

extern "C" void kernel_launch(void* const* d_in, const int* in_sizes, int n_in,
                              void* d_out, int out_size, void* d_ws, size_t ws_size,
                              hipStream_t stream) {
    const float* preds   = (const float*)d_in[0];
    const float* targets = (const float*)d_in[1];
    float* wsL = (float*)d_ws;
    float* wsV = wsL + GRID;
    float* out = (float*)d_out;

    reg_loss_main<<<GRID, BLOCK, 0, stream>>>(preds, targets, wsL, wsV);
    reg_loss_finalize<<<1, BLOCK, 0, stream>>>(wsL, wsV, out);
}